// Round 1
// baseline (450.820 us; speedup 1.0000x reference)
//
#include <hip/hip_runtime.h>

#define DEVI __device__ __forceinline__

typedef float  f32x4  __attribute__((ext_vector_type(4)));
typedef float  f32x16 __attribute__((ext_vector_type(16)));
typedef short  s16x8  __attribute__((ext_vector_type(8)));

DEVI void gload16(const void* g, void* l) {
  __builtin_amdgcn_global_load_lds(
      (const __attribute__((address_space(1))) void*)g,
      (__attribute__((address_space(3))) void*)l, 16, 0, 0);
}

DEVI ushort f2b(float f) {
  unsigned u = __builtin_bit_cast(unsigned, f);
  unsigned r = (u + 0x7fffu + ((u >> 16) & 1u)) >> 16;
  return (ushort)r;
}
DEVI unsigned pack2(float a, float b) {
  return (unsigned)f2b(a) | ((unsigned)f2b(b) << 16);
}

DEVI f32x4 mfma16(s16x8 a, s16x8 b, f32x4 c) {
  return __builtin_amdgcn_mfma_f32_16x16x32_bf16(a, b, c, 0, 0, 0);
}
DEVI f32x16 mfma32(s16x8 a, s16x8 b, f32x16 c) {
  return __builtin_amdgcn_mfma_f32_32x32x16_bf16(a, b, c, 0, 0, 0);
}

// ---------------------------------------------------------------------------
// K0: compose weights.  wqkvT[j][i] = sum_c w_sr[i][c]*W_{q|k|v}[c][j] (bf16,
// stored [768][1024]); bqkv[j] = b_sr @ W + b; woT[n][k] = w_o[k][n] (bf16).
// ---------------------------------------------------------------------------
__global__ __launch_bounds__(256) void k_compose(
    const float* __restrict__ w_sr, const float* __restrict__ b_sr,
    const float* __restrict__ w_q, const float* __restrict__ b_q,
    const float* __restrict__ w_k, const float* __restrict__ b_k,
    const float* __restrict__ w_v, const float* __restrict__ b_v,
    const float* __restrict__ w_o,
    ushort* __restrict__ wqkvT, ushort* __restrict__ woT, float* __restrict__ bqkv)
{
  const int b = blockIdx.x, t = threadIdx.x;
  if (b < 256) {
    const int i0 = b * 4;
    float acc[4][3] = {};
    for (int c = 0; c < 256; ++c) {
      float wq = w_q[c * 256 + t], wk = w_k[c * 256 + t], wv = w_v[c * 256 + t];
#pragma unroll
      for (int r = 0; r < 4; ++r) {
        float a = w_sr[(i0 + r) * 256 + c];  // uniform per block -> scalar load
        acc[r][0] += a * wq; acc[r][1] += a * wk; acc[r][2] += a * wv;
      }
    }
#pragma unroll
    for (int r = 0; r < 4; ++r) {
      wqkvT[(size_t)(t)       * 1024 + i0 + r] = f2b(acc[r][0]);
      wqkvT[(size_t)(256 + t) * 1024 + i0 + r] = f2b(acc[r][1]);
      wqkvT[(size_t)(512 + t) * 1024 + i0 + r] = f2b(acc[r][2]);
    }
  } else if (b == 256) {
    float a0 = b_q[t], a1 = b_k[t], a2 = b_v[t];
    for (int c = 0; c < 256; ++c) {
      float bs = b_sr[c];
      a0 += bs * w_q[c * 256 + t];
      a1 += bs * w_k[c * 256 + t];
      a2 += bs * w_v[c * 256 + t];
    }
    bqkv[t] = a0; bqkv[256 + t] = a1; bqkv[512 + t] = a2;
  } else {
    const int kk = b - 257;  // 0..255
#pragma unroll
    for (int n = t; n < 1024; n += 256)
      woT[(size_t)n * 256 + kk] = f2b(w_o[(size_t)kk * 1024 + n]);
  }
}

// ---------------------------------------------------------------------------
// K2: QKV GEMM.  C[32768,768] = X_f32[32768,1024] * WT^T + bias.
// A staged fp32 in LDS (cvt->bf16 at frag read), B bf16 from WT [N][K].
// Outputs: Q,K row-major bf16 [8][4096][256]; V transposed [8][256][4096].
// XOR swizzles applied via pre-swizzled GLOBAL source (linear LDS dest).
// ---------------------------------------------------------------------------
__global__ __launch_bounds__(256) void k_gemm_qkv(
    const float* __restrict__ X, const ushort* __restrict__ WT,
    const float* __restrict__ bias,
    ushort* __restrict__ Qo, ushort* __restrict__ Ko, ushort* __restrict__ VTo)
{
  __shared__ float  As[128 * 32];
  __shared__ ushort Bs[128 * 32];
  const int tid = threadIdx.x;
  const int l = tid & 63, w = tid >> 6;
  const int wr = w >> 1, wc = w & 1;
  const int g = l >> 4, lr = l & 15;
  const int tM = blockIdx.x * 128, tN = blockIdx.y * 128;
  f32x4 acc[4][4] = {};

  for (int kt = 0; kt < 32; ++kt) {
    const int k0 = kt * 32;
#pragma unroll
    for (int j = 0; j < 4; ++j) {  // A: 16 KB fp32
      int chunk = j * 256 + tid;
      int row = chunk >> 3, kc = chunk & 7;
      gload16(X + (size_t)(tM + row) * 1024 + k0 + ((kc ^ (row & 7)) << 2),
              (char*)As + (j * 256 + w * 64) * 16);
    }
#pragma unroll
    for (int j = 0; j < 2; ++j) {  // B: 8 KB bf16
      int chunk = j * 256 + tid;
      int row = chunk >> 2, kc = chunk & 3;
      gload16(WT + (size_t)(tN + row) * 1024 + k0 + ((kc ^ (row & 3)) << 3),
              (char*)Bs + (j * 256 + w * 64) * 16);
    }
    __syncthreads();
    s16x8 bfr[4];
#pragma unroll
    for (int ni = 0; ni < 4; ++ni) {
      int col = wc * 64 + ni * 16 + lr;
      bfr[ni] = *(const s16x8*)&Bs[col * 32 + ((g ^ (col & 3)) << 3)];
    }
#pragma unroll
    for (int mi = 0; mi < 4; ++mi) {
      int row = wr * 64 + mi * 16 + lr;
      int c1 = (2 * g) ^ (row & 7);
      int c2 = (2 * g + 1) ^ (row & 7);
      f32x4 a0 = *(const f32x4*)&As[row * 32 + c1 * 4];
      f32x4 a1 = *(const f32x4*)&As[row * 32 + c2 * 4];
      s16x8 af;
      af[0] = f2b(a0[0]); af[1] = f2b(a0[1]); af[2] = f2b(a0[2]); af[3] = f2b(a0[3]);
      af[4] = f2b(a1[0]); af[5] = f2b(a1[1]); af[6] = f2b(a1[2]); af[7] = f2b(a1[3]);
#pragma unroll
      for (int ni = 0; ni < 4; ++ni)
        acc[mi][ni] = mfma16(af, bfr[ni], acc[mi][ni]);
    }
    __syncthreads();
  }
#pragma unroll
  for (int ni = 0; ni < 4; ++ni) {
    const int col = tN + wc * 64 + ni * 16 + lr;
    const float bv = bias[col];
#pragma unroll
    for (int mi = 0; mi < 4; ++mi) {
      const int r0 = tM + wr * 64 + mi * 16 + g * 4;
      f32x4 c = acc[mi][ni];
      if (col < 512) {
        ushort* dst = (col < 256) ? Qo : Ko;
        const int cc = col & 255;
#pragma unroll
        for (int j = 0; j < 4; ++j)
          dst[(size_t)(r0 + j) * 256 + cc] = f2b(c[j] + bv);
      } else {
        const int d = col - 512;
        const int n = r0 >> 12, lrr = r0 & 4095;
        ushort4 pv;
        pv.x = f2b(c[0] + bv); pv.y = f2b(c[1] + bv);
        pv.z = f2b(c[2] + bv); pv.w = f2b(c[3] + bv);
        *(ushort4*)&VTo[(size_t)n * 256 * 4096 + (size_t)d * 4096 + lrr] = pv;
      }
    }
  }
}

// ---------------------------------------------------------------------------
// K3: flash attention.  256 blocks (batch = blockIdx&7 -> XCD), 4 waves x 32
// q-rows.  Swapped QK^T (S^T = K*Q^T) -> lane-local softmax; P packed in
// registers with half-swap shuffles; O accumulated transposed.  32x32x16 MFMA.
// ---------------------------------------------------------------------------
#define KSC 0.0901687369f  /* log2(e)/sqrt(256) */

__global__ __launch_bounds__(256) void k_flash(
    const ushort* __restrict__ Qg, const ushort* __restrict__ Kg,
    const ushort* __restrict__ VTg, ushort* __restrict__ Og)
{
  __shared__ ushort Ks[2][64 * 256];
  __shared__ ushort Vs[2][256 * 64];
  const int tid = threadIdx.x;
  const int l = tid & 63, w = tid >> 6;
  const int by = blockIdx.x & 7;
  const int qt = blockIdx.x >> 3;
  const int q0 = qt * 128 + w * 32;
  const int cl = l & 31, h = l >> 5;
  const size_t qrow = (size_t)by * 4096 + q0 + cl;

  s16x8 qf[16];
#pragma unroll
  for (int s = 0; s < 16; ++s)
    qf[s] = *(const s16x8*)&Qg[qrow * 256 + s * 16 + h * 8];

  f32x16 ot[8] = {};
  float m_run = -1e30f, l_run = 0.0f;

  auto stage = [&](int kt, int buf) {
    const ushort* kbase = Kg + (size_t)by * 4096 * 256 + (size_t)kt * 64 * 256;
#pragma unroll
    for (int j = 0; j < 8; ++j) {
      int chunk = j * 256 + tid;
      int row = chunk >> 5, kc = chunk & 31;
      gload16(kbase + row * 256 + ((kc ^ (row & 7)) << 3),
              (char*)Ks[buf] + (j * 256 + w * 64) * 16);
    }
    const ushort* vbase = VTg + (size_t)by * 256 * 4096 + kt * 64;
#pragma unroll
    for (int j = 0; j < 8; ++j) {
      int chunk = j * 256 + tid;
      int row = chunk >> 3, kc = chunk & 7;
      gload16(vbase + (size_t)row * 4096 + ((kc ^ (row & 7)) << 3),
              (char*)Vs[buf] + (j * 256 + w * 64) * 16);
    }
  };

  stage(0, 0);
  __syncthreads();

  for (int kt = 0; kt < 64; ++kt) {
    const int buf = kt & 1;
    if (kt + 1 < 64) stage(kt + 1, buf ^ 1);
    const ushort* KT  = Ks[buf];
    const ushort* VTt = Vs[buf];

    // S^T = K * Q^T   (lane: col = own q-row, regs = keys)
    f32x16 sa[2] = {};
#pragma unroll
    for (int mf = 0; mf < 2; ++mf) {
      const int key = mf * 32 + cl;
      const int base = key * 256, sw = key & 7;
#pragma unroll
      for (int s = 0; s < 16; ++s) {
        s16x8 a = *(const s16x8*)&KT[base + (((2 * s + h) ^ sw) << 3)];
        sa[mf] = mfma32(a, qf[s], sa[mf]);
      }
    }
    // softmax (raw logits; scale folded into KSC)
    float pmax = sa[0][0];
#pragma unroll
    for (int i = 1; i < 16; ++i) pmax = fmaxf(pmax, sa[0][i]);
#pragma unroll
    for (int i = 0; i < 16; ++i) pmax = fmaxf(pmax, sa[1][i]);
    pmax = fmaxf(pmax, __shfl_xor(pmax, 32));
    if (!__all(pmax <= m_run + 120.0f)) {   // defer-max (T13)
      float m_new = fmaxf(m_run, pmax);
      float corr = exp2f((m_run - m_new) * KSC);
      l_run *= corr;
#pragma unroll
      for (int mf = 0; mf < 8; ++mf)
#pragma unroll
        for (int i = 0; i < 16; ++i) ot[mf][i] *= corr;
      m_run = m_new;
    }
    unsigned pk[8][2];
    float lp = 0.0f;
#pragma unroll
    for (int mf = 0; mf < 2; ++mf)
#pragma unroll
      for (int gq = 0; gq < 4; ++gq) {
        float p0 = exp2f((sa[mf][4 * gq + 0] - m_run) * KSC);
        float p1 = exp2f((sa[mf][4 * gq + 1] - m_run) * KSC);
        float p2 = exp2f((sa[mf][4 * gq + 2] - m_run) * KSC);
        float p3 = exp2f((sa[mf][4 * gq + 3] - m_run) * KSC);
        lp += (p0 + p1) + (p2 + p3);
        pk[mf * 4 + gq][0] = pack2(p0, p1);
        pk[mf * 4 + gq][1] = pack2(p2, p3);
      }
    lp += __shfl_xor(lp, 32);
    l_run += lp;
    // PV: O^T += V^T * P^T  (B-frag assembled in-register via half swaps)
#pragma unroll
    for (int ks = 0; ks < 4; ++ks) {
      unsigned pp0 = __shfl_xor(pk[2 * ks][0], 32);
      unsigned pp1 = __shfl_xor(pk[2 * ks][1], 32);
      unsigned pq0 = __shfl_xor(pk[2 * ks + 1][0], 32);
      unsigned pq1 = __shfl_xor(pk[2 * ks + 1][1], 32);
      union { unsigned u[4]; s16x8 v; } pu;
      pu.u[0] = h ? pq0 : pk[2 * ks][0];
      pu.u[1] = h ? pq1 : pk[2 * ks][1];
      pu.u[2] = h ? pk[2 * ks + 1][0] : pp0;
      pu.u[3] = h ? pk[2 * ks + 1][1] : pp1;
      const s16x8 pf = pu.v;
#pragma unroll
      for (int mf = 0; mf < 8; ++mf) {
        const int d = mf * 32 + cl;
        s16x8 va = *(const s16x8*)&VTt[d * 64 + (((2 * ks + h) ^ (d & 7)) << 3)];
        ot[mf] = mfma32(va, pf, ot[mf]);
      }
    }
    __syncthreads();
  }

  const float rl = 1.0f / l_run;
#pragma unroll
  for (int mf = 0; mf < 8; ++mf)
#pragma unroll
    for (int c = 0; c < 4; ++c) {
      const int d0 = mf * 32 + 8 * c + 4 * h;
      ushort4 pv;
      pv.x = f2b(ot[mf][4 * c + 0] * rl);
      pv.y = f2b(ot[mf][4 * c + 1] * rl);
      pv.z = f2b(ot[mf][4 * c + 2] * rl);
      pv.w = f2b(ot[mf][4 * c + 3] * rl);
      *(ushort4*)&Og[qrow * 256 + d0] = pv;
    }
}

// ---------------------------------------------------------------------------
// K4: out projection.  OUT_f32[32768,1024] = O_bf16[32768,256] * WOT^T + b_o.
// ---------------------------------------------------------------------------
__global__ __launch_bounds__(256) void k_gemm_out(
    const ushort* __restrict__ Oi, const ushort* __restrict__ WT,
    const float* __restrict__ bias, float* __restrict__ OUT)
{
  __shared__ ushort As[128 * 32];
  __shared__ ushort Bs[128 * 32];
  const int tid = threadIdx.x;
  const int l = tid & 63, w = tid >> 6;
  const int wr = w >> 1, wc = w & 1;
  const int g = l >> 4, lr = l & 15;
  const int tM = blockIdx.x * 128, tN = blockIdx.y * 128;
  f32x4 acc[4][4] = {};

  for (int kt = 0; kt < 8; ++kt) {
    const int k0 = kt * 32;
#pragma unroll
    for (int j = 0; j < 2; ++j) {
      int chunk = j * 256 + tid;
      int row = chunk >> 2, kc = chunk & 3;
      gload16(Oi + (size_t)(tM + row) * 256 + k0 + ((kc ^ (row & 3)) << 3),
              (char*)As + (j * 256 + w * 64) * 16);
      gload16(WT + (size_t)(tN + row) * 256 + k0 + ((kc ^ (row & 3)) << 3),
              (char*)Bs + (j * 256 + w * 64) * 16);
    }
    __syncthreads();
    s16x8 afr[4], bfr[4];
#pragma unroll
    for (int ni = 0; ni < 4; ++ni) {
      int col = wc * 64 + ni * 16 + lr;
      bfr[ni] = *(const s16x8*)&Bs[col * 32 + ((g ^ (col & 3)) << 3)];
    }
#pragma unroll
    for (int mi = 0; mi < 4; ++mi) {
      int row = wr * 64 + mi * 16 + lr;
      afr[mi] = *(const s16x8*)&As[row * 32 + ((g ^ (row & 3)) << 3)];
    }
#pragma unroll
    for (int mi = 0; mi < 4; ++mi)
#pragma unroll
      for (int ni = 0; ni < 4; ++ni)
        acc[mi][ni] = mfma16(afr[mi], bfr[ni], acc[mi][ni]);
    __syncthreads();
  }
#pragma unroll
  for (int ni = 0; ni < 4; ++ni) {
    const int col = tN + wc * 64 + ni * 16 + lr;
    const float bv = bias[col];
#pragma unroll
    for (int mi = 0; mi < 4; ++mi) {
      const int r0 = tM + wr * 64 + mi * 16 + g * 4;
      f32x4 c = acc[mi][ni];
#pragma unroll
      for (int j = 0; j < 4; ++j)
        OUT[(size_t)(r0 + j) * 1024 + col] = c[j] + bv;
    }
  }
}

// ---------------------------------------------------------------------------
extern "C" void kernel_launch(void* const* d_in, const int* in_sizes, int n_in,
                              void* d_out, int out_size, void* d_ws, size_t ws_size,
                              hipStream_t stream) {
  const float* x    = (const float*)d_in[0];
  const float* w_sr = (const float*)d_in[1];
  const float* b_sr = (const float*)d_in[2];
  const float* w_q  = (const float*)d_in[3];
  const float* b_q  = (const float*)d_in[4];
  const float* w_k  = (const float*)d_in[5];
  const float* b_k  = (const float*)d_in[6];
  const float* w_v  = (const float*)d_in[7];
  const float* b_v  = (const float*)d_in[8];
  const float* w_o  = (const float*)d_in[9];
  const float* b_o  = (const float*)d_in[10];
  float* out = (float*)d_out;

  char* ws = (char*)d_ws;
  const size_t MB = 1024 * 1024;
  ushort* Q     = (ushort*)(ws);
  ushort* K     = (ushort*)(ws + 16 * MB);
  ushort* VT    = (ushort*)(ws + 32 * MB);
  ushort* O     = (ushort*)(ws + 48 * MB);
  ushort* WQKVT = (ushort*)(ws + 64 * MB);
  ushort* WOT   = (ushort*)(ws + 66 * MB);
  float*  BQKV  = (float*) (ws + 67 * MB);

  k_compose<<<513, 256, 0, stream>>>(w_sr, b_sr, w_q, b_q, w_k, b_k, w_v, b_v,
                                     w_o, WQKVT, WOT, BQKV);
  k_gemm_qkv<<<dim3(256, 6), 256, 0, stream>>>(x, WQKVT, BQKV, Q, K, VT);
  k_flash<<<256, 256, 0, stream>>>(Q, K, VT, O);
  k_gemm_out<<<dim3(256, 8), 256, 0, stream>>>(O, WOT, b_o, out);
}

// Round 2
// 403.446 us; speedup vs baseline: 1.1174x; 1.1174x over previous
//
#include <hip/hip_runtime.h>

#define DEVI __device__ __forceinline__

typedef float  f32x4  __attribute__((ext_vector_type(4)));
typedef float  f32x16 __attribute__((ext_vector_type(16)));
typedef short  s16x8  __attribute__((ext_vector_type(8)));

DEVI void gload16(const void* g, void* l) {
  __builtin_amdgcn_global_load_lds(
      (const __attribute__((address_space(1))) void*)g,
      (__attribute__((address_space(3))) void*)l, 16, 0, 0);
}

DEVI ushort f2b(float f) {
  unsigned u = __builtin_bit_cast(unsigned, f);
  unsigned r = (u + 0x7fffu + ((u >> 16) & 1u)) >> 16;
  return (ushort)r;
}
DEVI unsigned pack2(float a, float b) {
  return (unsigned)f2b(a) | ((unsigned)f2b(b) << 16);
}
DEVI float b2f(short s) {
  return __builtin_bit_cast(float, (unsigned)((ushort)s) << 16);
}

DEVI f32x4 mfma16(s16x8 a, s16x8 b, f32x4 c) {
  return __builtin_amdgcn_mfma_f32_16x16x32_bf16(a, b, c, 0, 0, 0);
}
DEVI f32x16 mfma32(s16x8 a, s16x8 b, f32x16 c) {
  return __builtin_amdgcn_mfma_f32_32x32x16_bf16(a, b, c, 0, 0, 0);
}

// ---------------------------------------------------------------------------
// K0: compose weights.  wqkvT[j][i] = sum_c w_sr[i][c]*W_{q|k|v}[c][j] (bf16,
// stored [768][1024]); bqkv[j] = b_sr @ W + b; woT[n][k] = w_o[k][n] (bf16).
// ---------------------------------------------------------------------------
__global__ __launch_bounds__(256) void k_compose(
    const float* __restrict__ w_sr, const float* __restrict__ b_sr,
    const float* __restrict__ w_q, const float* __restrict__ b_q,
    const float* __restrict__ w_k, const float* __restrict__ b_k,
    const float* __restrict__ w_v, const float* __restrict__ b_v,
    const float* __restrict__ w_o,
    ushort* __restrict__ wqkvT, ushort* __restrict__ woT, float* __restrict__ bqkv)
{
  const int b = blockIdx.x, t = threadIdx.x;
  if (b < 256) {
    const int i0 = b * 4;
    float acc[4][3] = {};
    for (int c = 0; c < 256; ++c) {
      float wq = w_q[c * 256 + t], wk = w_k[c * 256 + t], wv = w_v[c * 256 + t];
#pragma unroll
      for (int r = 0; r < 4; ++r) {
        float a = w_sr[(i0 + r) * 256 + c];  // uniform per block -> scalar load
        acc[r][0] += a * wq; acc[r][1] += a * wk; acc[r][2] += a * wv;
      }
    }
#pragma unroll
    for (int r = 0; r < 4; ++r) {
      wqkvT[(size_t)(t)       * 1024 + i0 + r] = f2b(acc[r][0]);
      wqkvT[(size_t)(256 + t) * 1024 + i0 + r] = f2b(acc[r][1]);
      wqkvT[(size_t)(512 + t) * 1024 + i0 + r] = f2b(acc[r][2]);
    }
  } else if (b == 256) {
    float a0 = b_q[t], a1 = b_k[t], a2 = b_v[t];
    for (int c = 0; c < 256; ++c) {
      float bs = b_sr[c];
      a0 += bs * w_q[c * 256 + t];
      a1 += bs * w_k[c * 256 + t];
      a2 += bs * w_v[c * 256 + t];
    }
    bqkv[t] = a0; bqkv[256 + t] = a1; bqkv[512 + t] = a2;
  } else {
    const int kk = b - 257;  // 0..255
#pragma unroll
    for (int n = t; n < 1024; n += 256)
      woT[(size_t)n * 256 + kk] = f2b(w_o[(size_t)kk * 1024 + n]);
  }
}

// ---------------------------------------------------------------------------
// K2: QKV GEMM.  C[32768,768] = X_f32[32768,1024] * WT^T + bias.
// A staged fp32 in LDS (cvt->bf16 at frag read), B bf16 from WT [N][K].
// Outputs: Q,K row-major bf16 [8][4096][256]; V transposed [8][256][4096].
// ---------------------------------------------------------------------------
__global__ __launch_bounds__(256) void k_gemm_qkv(
    const float* __restrict__ X, const ushort* __restrict__ WT,
    const float* __restrict__ bias,
    ushort* __restrict__ Qo, ushort* __restrict__ Ko, ushort* __restrict__ VTo)
{
  __shared__ float  As[128 * 32];
  __shared__ ushort Bs[128 * 32];
  const int tid = threadIdx.x;
  const int l = tid & 63, w = tid >> 6;
  const int wr = w >> 1, wc = w & 1;
  const int g = l >> 4, lr = l & 15;
  const int tM = blockIdx.x * 128, tN = blockIdx.y * 128;
  f32x4 acc[4][4] = {};

  for (int kt = 0; kt < 32; ++kt) {
    const int k0 = kt * 32;
#pragma unroll
    for (int j = 0; j < 4; ++j) {  // A: 16 KB fp32
      int chunk = j * 256 + tid;
      int row = chunk >> 3, kc = chunk & 7;
      gload16(X + (size_t)(tM + row) * 1024 + k0 + ((kc ^ (row & 7)) << 2),
              (char*)As + (j * 256 + w * 64) * 16);
    }
#pragma unroll
    for (int j = 0; j < 2; ++j) {  // B: 8 KB bf16
      int chunk = j * 256 + tid;
      int row = chunk >> 2, kc = chunk & 3;
      gload16(WT + (size_t)(tN + row) * 1024 + k0 + ((kc ^ (row & 3)) << 3),
              (char*)Bs + (j * 256 + w * 64) * 16);
    }
    __syncthreads();
    s16x8 bfr[4];
#pragma unroll
    for (int ni = 0; ni < 4; ++ni) {
      int col = wc * 64 + ni * 16 + lr;
      bfr[ni] = *(const s16x8*)&Bs[col * 32 + ((g ^ (col & 3)) << 3)];
    }
#pragma unroll
    for (int mi = 0; mi < 4; ++mi) {
      int row = wr * 64 + mi * 16 + lr;
      int c1 = (2 * g) ^ (row & 7);
      int c2 = (2 * g + 1) ^ (row & 7);
      f32x4 a0 = *(const f32x4*)&As[row * 32 + c1 * 4];
      f32x4 a1 = *(const f32x4*)&As[row * 32 + c2 * 4];
      s16x8 af;
      af[0] = f2b(a0[0]); af[1] = f2b(a0[1]); af[2] = f2b(a0[2]); af[3] = f2b(a0[3]);
      af[4] = f2b(a1[0]); af[5] = f2b(a1[1]); af[6] = f2b(a1[2]); af[7] = f2b(a1[3]);
#pragma unroll
      for (int ni = 0; ni < 4; ++ni)
        acc[mi][ni] = mfma16(af, bfr[ni], acc[mi][ni]);
    }
    __syncthreads();
  }
#pragma unroll
  for (int ni = 0; ni < 4; ++ni) {
    const int col = tN + wc * 64 + ni * 16 + lr;
    const float bv = bias[col];
#pragma unroll
    for (int mi = 0; mi < 4; ++mi) {
      const int r0 = tM + wr * 64 + mi * 16 + g * 4;
      f32x4 c = acc[mi][ni];
      if (col < 512) {
        ushort* dst = (col < 256) ? Qo : Ko;
        const int cc = col & 255;
#pragma unroll
        for (int j = 0; j < 4; ++j)
          dst[(size_t)(r0 + j) * 256 + cc] = f2b(c[j] + bv);
      } else {
        const int d = col - 512;
        const int n = r0 >> 12, lrr = r0 & 4095;
        ushort4 pv;
        pv.x = f2b(c[0] + bv); pv.y = f2b(c[1] + bv);
        pv.z = f2b(c[2] + bv); pv.w = f2b(c[3] + bv);
        *(ushort4*)&VTo[(size_t)n * 256 * 4096 + (size_t)d * 4096 + lrr] = pv;
      }
    }
  }
}

// ---------------------------------------------------------------------------
// K3: flash attention.  4 waves x 32 q-rows, KBLK=32 double-buffered (64 KiB
// LDS -> 2 blocks/CU).  Conflict-free LDS layouts: K as [dslot][key][8],
// V as [kvslot][d][8] (every ds_read_b128 wave-contiguous).  Optional 2-way
// KV split (NSPLIT=2): 512 blocks -> 8 waves/CU, partials + combine pass.
// ---------------------------------------------------------------------------
#define KSC 0.0901687369f  /* log2(e)/sqrt(256) */

template<int NSPLIT>
__global__ __launch_bounds__(256, 2) void k_flash(
    const ushort* __restrict__ Qg, const ushort* __restrict__ Kg,
    const ushort* __restrict__ VTg, ushort* __restrict__ Po, float* __restrict__ MLo)
{
  __shared__ ushort Ks[2][8192];   // [buf][dslot(32)][key(32)][8]
  __shared__ ushort Vs[2][8192];   // [buf][kvslot(4)][d(256)][8]
  const int tid = threadIdx.x;
  const int l = tid & 63, w = tid >> 6;
  const int by = blockIdx.x & 7;                       // batch -> XCD
  const int rest = blockIdx.x >> 3;
  const int split = (NSPLIT == 2) ? (rest & 1) : 0;
  const int qt = (NSPLIT == 2) ? (rest >> 1) : rest;
  const int NT = (NSPLIT == 2) ? 64 : 128;
  const int kv0 = split * 2048;
  const int q0 = qt * 128 + w * 32;
  const int cl = l & 31, h = l >> 5;
  const size_t qrow = (size_t)by * 4096 + q0 + cl;

  s16x8 qf[16];
#pragma unroll
  for (int s = 0; s < 16; ++s)
    qf[s] = *(const s16x8*)&Qg[qrow * 256 + s * 16 + h * 8];

  f32x16 ot[8] = {};
  float m_run = -1e30f, l_run = 0.0f;

  const ushort* kb0 = Kg + ((size_t)by * 4096 + kv0) * 256;
  const ushort* vb0 = VTg + (size_t)by * 256 * 4096 + kv0;

  auto stage = [&](int t, int buf) {
    const ushort* kb = kb0 + t * 32 * 256;
#pragma unroll
    for (int j = 0; j < 4; ++j) {
      int chunk = j * 256 + tid;                 // key = chunk&31, dslot = chunk>>5
      gload16(kb + (chunk & 31) * 256 + (chunk >> 5) * 8,
              &Ks[buf][(j * 256 + w * 64) * 8]);
    }
    const ushort* vb = vb0 + t * 32;
#pragma unroll
    for (int j = 0; j < 4; ++j) {
      int chunk = j * 256 + tid;                 // d = chunk&255, kvslot = chunk>>8
      gload16(vb + (size_t)(chunk & 255) * 4096 + (chunk >> 8) * 8,
              &Vs[buf][(j * 256 + w * 64) * 8]);
    }
  };

  stage(0, 0);
  __syncthreads();

  for (int t = 0; t < NT; ++t) {
    const int buf = t & 1;
    if (t + 1 < NT) stage(t + 1, buf ^ 1);
    const ushort* KT = Ks[buf];

    // S^T = K * Q^T : lane (cl,h) accumulates 16 keys for q-row cl
    f32x16 sa = {};
    __builtin_amdgcn_s_setprio(1);
#pragma unroll
    for (int s = 0; s < 16; ++s) {
      s16x8 a = *(const s16x8*)&KT[(2 * s + h) * 256 + cl * 8];
      sa = mfma32(a, qf[s], sa);
    }
    __builtin_amdgcn_s_setprio(0);

    // softmax over 32 keys (16 local + half-swap)
    float t0 = fmaxf(fmaxf(sa[0], sa[1]), fmaxf(sa[2], sa[3]));
    float t1 = fmaxf(fmaxf(sa[4], sa[5]), fmaxf(sa[6], sa[7]));
    float t2 = fmaxf(fmaxf(sa[8], sa[9]), fmaxf(sa[10], sa[11]));
    float t3 = fmaxf(fmaxf(sa[12], sa[13]), fmaxf(sa[14], sa[15]));
    float pmax = fmaxf(fmaxf(t0, t1), fmaxf(t2, t3));
    pmax = fmaxf(pmax, __shfl_xor(pmax, 32));
    if (!__all(pmax <= m_run + 120.0f)) {        // defer-max (T13)
      float m_new = fmaxf(m_run, pmax);
      float corr = exp2f((m_run - m_new) * KSC);
      l_run *= corr;
#pragma unroll
      for (int mf = 0; mf < 8; ++mf)
#pragma unroll
        for (int i = 0; i < 16; ++i) ot[mf][i] *= corr;
      m_run = m_new;
    }
    unsigned pk[4][2];
    float lp = 0.0f;
#pragma unroll
    for (int gq = 0; gq < 4; ++gq) {
      float p0 = exp2f((sa[4 * gq + 0] - m_run) * KSC);
      float p1 = exp2f((sa[4 * gq + 1] - m_run) * KSC);
      float p2 = exp2f((sa[4 * gq + 2] - m_run) * KSC);
      float p3 = exp2f((sa[4 * gq + 3] - m_run) * KSC);
      lp += (p0 + p1) + (p2 + p3);
      pk[gq][0] = pack2(p0, p1);
      pk[gq][1] = pack2(p2, p3);
    }
    lp += __shfl_xor(lp, 32);
    l_run += lp;

    // PV: O^T += V^T * P^T
    const ushort* VT2 = Vs[buf];
#pragma unroll
    for (int ks = 0; ks < 2; ++ks) {
      unsigned pp0 = __shfl_xor(pk[2 * ks][0], 32);
      unsigned pp1 = __shfl_xor(pk[2 * ks][1], 32);
      unsigned pq0 = __shfl_xor(pk[2 * ks + 1][0], 32);
      unsigned pq1 = __shfl_xor(pk[2 * ks + 1][1], 32);
      union { unsigned u[4]; s16x8 v; } pu;
      pu.u[0] = h ? pq0 : pk[2 * ks][0];
      pu.u[1] = h ? pq1 : pk[2 * ks][1];
      pu.u[2] = h ? pk[2 * ks + 1][0] : pp0;
      pu.u[3] = h ? pk[2 * ks + 1][1] : pp1;
      const s16x8 pf = pu.v;
      __builtin_amdgcn_s_setprio(1);
#pragma unroll
      for (int mf = 0; mf < 8; ++mf) {
        s16x8 va = *(const s16x8*)&VT2[(2 * ks + h) * 2048 + (mf * 32 + cl) * 8];
        ot[mf] = mfma32(va, pf, ot[mf]);
      }
      __builtin_amdgcn_s_setprio(0);
    }
    __syncthreads();
  }

  const float rl = 1.0f / l_run;
  const size_t orow = (size_t)split * 32768 + qrow;
#pragma unroll
  for (int mf = 0; mf < 8; ++mf)
#pragma unroll
    for (int c = 0; c < 4; ++c) {
      const int d0 = mf * 32 + 8 * c + 4 * h;
      ushort4 pv;
      pv.x = f2b(ot[mf][4 * c + 0] * rl);
      pv.y = f2b(ot[mf][4 * c + 1] * rl);
      pv.z = f2b(ot[mf][4 * c + 2] * rl);
      pv.w = f2b(ot[mf][4 * c + 3] * rl);
      *(ushort4*)&Po[orow * 256 + d0] = pv;
    }
  if (NSPLIT == 2 && h == 0) {
    float2 ml; ml.x = m_run; ml.y = l_run;
    *(float2*)&MLo[orow * 2] = ml;
  }
}

// ---------------------------------------------------------------------------
// K3b: combine the two KV-split partials (in-place into partial0 slot).
// ---------------------------------------------------------------------------
__global__ __launch_bounds__(256) void k_combine(
    const ushort* __restrict__ P, const float* __restrict__ ML,
    ushort* __restrict__ Og)
{
  const int idx = blockIdx.x * 256 + threadIdx.x;    // 1,048,576 total
  const int r = idx >> 5, dc = (idx & 31) * 8;
  const float m0 = ML[(size_t)r * 2],             l0 = ML[(size_t)r * 2 + 1];
  const float m1 = ML[(size_t)(32768 + r) * 2],   l1 = ML[(size_t)(32768 + r) * 2 + 1];
  const float m  = fmaxf(m0, m1);
  const float a0 = l0 * exp2f((m0 - m) * KSC);
  const float a1 = l1 * exp2f((m1 - m) * KSC);
  const float inv = 1.0f / (a0 + a1);
  const float w0 = a0 * inv, w1 = a1 * inv;
  s16x8 x0 = *(const s16x8*)&P[(size_t)r * 256 + dc];
  s16x8 x1 = *(const s16x8*)&P[(size_t)(32768 + r) * 256 + dc];
  union { ushort u[8]; s16x8 v; } o;
#pragma unroll
  for (int j = 0; j < 8; ++j)
    o.u[j] = f2b(w0 * b2f(x0[j]) + w1 * b2f(x1[j]));
  *(s16x8*)&Og[(size_t)r * 256 + dc] = o.v;
}

// ---------------------------------------------------------------------------
// K4: out projection.  OUT_f32[32768,1024] = O_bf16[32768,256] * WOT^T + b_o.
// ---------------------------------------------------------------------------
__global__ __launch_bounds__(256) void k_gemm_out(
    const ushort* __restrict__ Oi, const ushort* __restrict__ WT,
    const float* __restrict__ bias, float* __restrict__ OUT)
{
  __shared__ ushort As[128 * 32];
  __shared__ ushort Bs[128 * 32];
  const int tid = threadIdx.x;
  const int l = tid & 63, w = tid >> 6;
  const int wr = w >> 1, wc = w & 1;
  const int g = l >> 4, lr = l & 15;
  const int tM = blockIdx.x * 128, tN = blockIdx.y * 128;
  f32x4 acc[4][4] = {};

  for (int kt = 0; kt < 8; ++kt) {
    const int k0 = kt * 32;
#pragma unroll
    for (int j = 0; j < 2; ++j) {
      int chunk = j * 256 + tid;
      int row = chunk >> 2, kc = chunk & 3;
      gload16(Oi + (size_t)(tM + row) * 256 + k0 + ((kc ^ (row & 3)) << 3),
              (char*)As + (j * 256 + w * 64) * 16);
      gload16(WT + (size_t)(tN + row) * 256 + k0 + ((kc ^ (row & 3)) << 3),
              (char*)Bs + (j * 256 + w * 64) * 16);
    }
    __syncthreads();
    s16x8 afr[4], bfr[4];
#pragma unroll
    for (int ni = 0; ni < 4; ++ni) {
      int col = wc * 64 + ni * 16 + lr;
      bfr[ni] = *(const s16x8*)&Bs[col * 32 + ((g ^ (col & 3)) << 3)];
    }
#pragma unroll
    for (int mi = 0; mi < 4; ++mi) {
      int row = wr * 64 + mi * 16 + lr;
      afr[mi] = *(const s16x8*)&As[row * 32 + ((g ^ (row & 3)) << 3)];
    }
#pragma unroll
    for (int mi = 0; mi < 4; ++mi)
#pragma unroll
      for (int ni = 0; ni < 4; ++ni)
        acc[mi][ni] = mfma16(afr[mi], bfr[ni], acc[mi][ni]);
    __syncthreads();
  }
#pragma unroll
  for (int ni = 0; ni < 4; ++ni) {
    const int col = tN + wc * 64 + ni * 16 + lr;
    const float bv = bias[col];
#pragma unroll
    for (int mi = 0; mi < 4; ++mi) {
      const int r0 = tM + wr * 64 + mi * 16 + g * 4;
      f32x4 c = acc[mi][ni];
#pragma unroll
      for (int j = 0; j < 4; ++j)
        OUT[(size_t)(r0 + j) * 1024 + col] = c[j] + bv;
    }
  }
}

// ---------------------------------------------------------------------------
extern "C" void kernel_launch(void* const* d_in, const int* in_sizes, int n_in,
                              void* d_out, int out_size, void* d_ws, size_t ws_size,
                              hipStream_t stream) {
  const float* x    = (const float*)d_in[0];
  const float* w_sr = (const float*)d_in[1];
  const float* b_sr = (const float*)d_in[2];
  const float* w_q  = (const float*)d_in[3];
  const float* b_q  = (const float*)d_in[4];
  const float* w_k  = (const float*)d_in[5];
  const float* b_k  = (const float*)d_in[6];
  const float* w_v  = (const float*)d_in[7];
  const float* b_v  = (const float*)d_in[8];
  const float* w_o  = (const float*)d_in[9];
  const float* b_o  = (const float*)d_in[10];
  float* out = (float*)d_out;

  char* ws = (char*)d_ws;
  const size_t MB = 1024 * 1024;
  const bool split = ws_size >= 84 * MB;

  ushort* Q  = (ushort*)(ws);
  ushort* K  = (ushort*)(ws + 16 * MB);
  ushort* VT = (ushort*)(ws + 32 * MB);
  ushort* P  = (ushort*)(ws + 48 * MB);      // [split0 | split1]; O lands in split0
  float*  ML = (float*) (ws + 80 * MB);
  ushort* WQKVT = split ? (ushort*)(ws + 80 * MB + 512 * 1024) : (ushort*)(ws + 64 * MB);
  ushort* WOT   = split ? (ushort*)(ws + 82 * MB + 512 * 1024) : (ushort*)(ws + 66 * MB);
  float*  BQKV  = split ? (float*) (ws + 83 * MB)              : (float*) (ws + 66 * MB + 512 * 1024);

  k_compose<<<513, 256, 0, stream>>>(w_sr, b_sr, w_q, b_q, w_k, b_k, w_v, b_v,
                                     w_o, WQKVT, WOT, BQKV);
  k_gemm_qkv<<<dim3(256, 6), 256, 0, stream>>>(x, WQKVT, BQKV, Q, K, VT);
  if (split) {
    k_flash<2><<<512, 256, 0, stream>>>(Q, K, VT, P, ML);
    k_combine<<<4096, 256, 0, stream>>>(P, ML, P);
  } else {
    k_flash<1><<<256, 256, 0, stream>>>(Q, K, VT, P, nullptr);
  }
  k_gemm_out<<<dim3(256, 8), 256, 0, stream>>>(P, WOT, b_o, out);
}